// Round 6
// baseline (223.871 us; speedup 1.0000x reference)
//
#include <hip/hip_runtime.h>
#include <math.h>

// Shapes: B=8, T=16, H=64, W=64, D=256, DK=128, TOP_K=4
// pixels N = B*H*W = 32768 (4096 per batch)
//
// Factorization: out = (sum_t attn_t * hist_t) @ (Wv@Wo)
//                score_t = (q @ (Wq@Wk^T)) . hist_t / sqrt(128)
// hist read exactly once, double-buffered in registers.
// Score path fully fp32 (top-k selection is precision-critical).
//
// R6: GEMM phases read the LDS A-tile via ds_read_b128 (4 k-values per DS
// op) instead of scalar ds_read_b32 broadcasts -> DS-issue time drops 4x,
// GEMM phases become VALU-bound (~27us each). Pixel 0's hist loads are
// issued before phase 0 so the stream overlaps the first GEMM.

// ---------------- Kernel P: M1 = Wq@Wk^T, M2 = Wv@Wo (256x256 each) -------
__global__ __launch_bounds__(256) void precompute_weights(
    const float* __restrict__ Wq, const float* __restrict__ Wk,
    const float* __restrict__ Wv, const float* __restrict__ Wo,
    float* __restrict__ M1, float* __restrict__ M2) {
  __shared__ float rowbuf[128];
  int bid = blockIdx.x, tid = threadIdx.x;
  if (bid < 256) {
    if (tid < 128) rowbuf[tid] = Wq[bid * 128 + tid];
    __syncthreads();
    const float4* Wk4 = (const float4*)Wk;
    const float4* rb4 = (const float4*)rowbuf;
    float acc = 0.f;
#pragma unroll 8
    for (int k4 = 0; k4 < 32; ++k4) {
      float4 a = rb4[k4];
      float4 b = Wk4[tid * 32 + k4];
      acc = fmaf(a.x, b.x, acc); acc = fmaf(a.y, b.y, acc);
      acc = fmaf(a.z, b.z, acc); acc = fmaf(a.w, b.w, acc);
    }
    M1[bid * 256 + tid] = acc;
  } else {
    int d = bid - 256;
    if (tid < 128) rowbuf[tid] = Wv[d * 128 + tid];
    __syncthreads();
    float acc = 0.f;
#pragma unroll 8
    for (int k = 0; k < 128; ++k)
      acc = fmaf(rowbuf[k], Wo[k * 256 + tid], acc);
    M2[d * 256 + tid] = acc;
  }
}

// Row-tile GEMM helper: acc(16 rows x 4 cols/lane) = As[r0..r0+15][:] @ Bm.
// A read as b128 broadcasts (uniform addr), Bm from global (L2-resident).
// k order ascending => bit-identical to scalar-k version.
#define TILE_GEMM(ACC, BM)                                                  \
  {                                                                         \
    const float4* B4 = (const float4*)(BM);                                 \
    _Pragma("unroll 2") for (int d4 = 0; d4 < 64; ++d4) {                   \
      float4 bv0 = B4[(4 * d4 + 0) * 64 + l];                               \
      float4 bv1 = B4[(4 * d4 + 1) * 64 + l];                               \
      float4 bv2 = B4[(4 * d4 + 2) * 64 + l];                               \
      float4 bv3 = B4[(4 * d4 + 3) * 64 + l];                               \
      _Pragma("unroll") for (int j = 0; j < 16; ++j) {                      \
        float4 a = *(const float4*)&As[r0 + j][4 * d4];                     \
        ACC[j].x = fmaf(a.x, bv0.x, ACC[j].x);                              \
        ACC[j].y = fmaf(a.x, bv0.y, ACC[j].y);                              \
        ACC[j].z = fmaf(a.x, bv0.z, ACC[j].z);                              \
        ACC[j].w = fmaf(a.x, bv0.w, ACC[j].w);                              \
        ACC[j].x = fmaf(a.y, bv1.x, ACC[j].x);                              \
        ACC[j].y = fmaf(a.y, bv1.y, ACC[j].y);                              \
        ACC[j].z = fmaf(a.y, bv1.z, ACC[j].z);                              \
        ACC[j].w = fmaf(a.y, bv1.w, ACC[j].w);                              \
        ACC[j].x = fmaf(a.z, bv2.x, ACC[j].x);                              \
        ACC[j].y = fmaf(a.z, bv2.y, ACC[j].y);                              \
        ACC[j].z = fmaf(a.z, bv2.z, ACC[j].z);                              \
        ACC[j].w = fmaf(a.z, bv2.w, ACC[j].w);                              \
        ACC[j].x = fmaf(a.w, bv3.x, ACC[j].x);                              \
        ACC[j].y = fmaf(a.w, bv3.y, ACC[j].y);                              \
        ACC[j].z = fmaf(a.w, bv3.z, ACC[j].z);                              \
        ACC[j].w = fmaf(a.w, bv3.w, ACC[j].w);                              \
      }                                                                     \
    }                                                                       \
  }

// ---------------- Mega-kernel: qm -> attention -> out-projection ----------
// 64 pixels/block, 4 waves, wave w owns rows w*16..w*16+15. NO barriers.
__global__ __launch_bounds__(256, 2) void fused_all(
    const float* __restrict__ query, const float* __restrict__ hist,
    const float* __restrict__ M1, const float* __restrict__ M2,
    float* __restrict__ OUT) {
  __shared__ float As[64][260];  // per-wave 16-row slice: query->qm->hbar
  int tid = threadIdx.x;
  int l = tid & 63;   // lane
  int w = tid >> 6;   // wave
  int pix0 = blockIdx.x * 64;
  int r0 = w * 16;    // this wave's first row

  // hist geometry (float4 units)
  const float4* H4 = (const float4*)hist;
  int b = pix0 >> 12;  // 64-pixel tile never crosses a batch
  int off0 = pix0 & 4095;
  size_t hblk = ((size_t)b * 16 * 4096 + off0) * 64 + l;

  // Prefetch pixel 0's hist tile BEFORE phase 0 (lands under the GEMM).
  float4 hA[16], hB[16];
#pragma unroll
  for (int t = 0; t < 16; ++t)
    hA[t] = H4[hblk + (size_t)r0 * 64 + (size_t)t * 262144];

  // ---------- phase 0: own 16 rows of qm = query @ M1 (fp32) ----------
  {
    const float4* Qb4 = (const float4*)(query + (size_t)pix0 * 256);
#pragma unroll
    for (int k = 0; k < 16; ++k)  // stage own rows (1KB contiguous each)
      *(float4*)&As[r0 + k][4 * l] = Qb4[(size_t)(r0 + k) * 64 + l];
    float4 acc[16];
#pragma unroll
    for (int j = 0; j < 16; ++j) acc[j] = make_float4(0.f, 0.f, 0.f, 0.f);
    TILE_GEMM(acc, M1);
    // all reads of query slice done (program order) -> overwrite with qm
#pragma unroll
    for (int j = 0; j < 16; ++j)
      *(float4*)&As[r0 + j][4 * l] = acc[j];
  }

  // ---------- phase 1: stream hist, score, top-4, softmax, hbar ----------
  int t_mine = l & 15;
  int gbase = l & 48;  // 16-lane replica group base

#define ATTN_STEP(HC, HN, IT, DOPRE)                                        \
  {                                                                         \
    int row = r0 + (IT);                                                    \
    if (DOPRE) { /* prefetch next pixel into HN while computing HC */       \
      size_t nb = hblk + (size_t)(row + 1) * 64;                            \
      _Pragma("unroll") for (int t = 0; t < 16; ++t)                        \
          HN[t] = H4[nb + (size_t)t * 262144];                              \
    }                                                                       \
    float4 q = *(const float4*)&As[row][4 * l];                             \
    float part[16];                                                         \
    _Pragma("unroll") for (int t = 0; t < 16; ++t) {                        \
      float s = HC[t].x * q.x;                                              \
      s = fmaf(HC[t].y, q.y, s);                                            \
      s = fmaf(HC[t].z, q.z, s);                                            \
      s = fmaf(HC[t].w, q.w, s);                                            \
      part[t] = s;                                                          \
    }                                                                       \
    _Pragma("unroll") for (int st = 0; st < 4; ++st) {                      \
      bool hi = (l >> st) & 1;                                              \
      int nt = 8 >> st;                                                     \
      _Pragma("unroll") for (int i = 0; i < nt; ++i) {                      \
        float mine = hi ? part[2 * i + 1] : part[2 * i];                    \
        float oth = hi ? part[2 * i] : part[2 * i + 1];                     \
        part[i] = mine + __shfl_xor(oth, 1 << st);                          \
      }                                                                     \
    }                                                                       \
    float v = part[0];                                                      \
    v += __shfl_xor(v, 16);                                                 \
    v += __shfl_xor(v, 32);                                                 \
    float sc = v * 0.08838834764831845f; /* 1/sqrt(128); t = l&15 */        \
    int rank = 0; /* exact lax.top_k: lowest-index tie-break */             \
    _Pragma("unroll") for (int k = 1; k < 16; ++k) {                        \
      int ot = (t_mine + k) & 15;                                           \
      float o = __shfl(sc, gbase | ot);                                     \
      rank += (o > sc) || (o == sc && ot < t_mine);                         \
    }                                                                       \
    bool chosen = rank < 4;                                                 \
    float earg = sc + (float)(16 - t_mine) * -0.05129329438755058f;         \
    float ex = chosen ? expf(earg) : 0.0f;                                  \
    float Z = ex;                                                           \
    Z += __shfl_xor(Z, 1);                                                  \
    Z += __shfl_xor(Z, 2);                                                  \
    Z += __shfl_xor(Z, 4);                                                  \
    Z += __shfl_xor(Z, 8);                                                  \
    float attn = ex / Z;                                                    \
    float4 hb = make_float4(0.f, 0.f, 0.f, 0.f);                            \
    _Pragma("unroll") for (int t = 0; t < 16; ++t) {                        \
      float a = __shfl(attn, gbase | t); /* uniform in value across wave */ \
      if (a != 0.0f) {                                                      \
        hb.x = fmaf(a, HC[t].x, hb.x);                                      \
        hb.y = fmaf(a, HC[t].y, hb.y);                                      \
        hb.z = fmaf(a, HC[t].z, hb.z);                                      \
        hb.w = fmaf(a, HC[t].w, hb.w);                                      \
      }                                                                     \
    }                                                                       \
    *(float4*)&As[row][4 * l] = hb; /* q already in reg; row wave-owned */  \
  }

  for (int it2 = 0; it2 < 8; ++it2) {
    ATTN_STEP(hA, hB, 2 * it2, true);
    ATTN_STEP(hB, hA, 2 * it2 + 1, it2 < 7);
  }
#undef ATTN_STEP

  // ---------- phase 2: own 16 rows of OUT = As(hbar) @ M2 ----------
  {
    float4 acc[16];
#pragma unroll
    for (int j = 0; j < 16; ++j) acc[j] = make_float4(0.f, 0.f, 0.f, 0.f);
    TILE_GEMM(acc, M2);
    float4* C4 = (float4*)(OUT + (size_t)pix0 * 256);
#pragma unroll
    for (int j = 0; j < 16; ++j)
      C4[(r0 + j) * 64 + l] = acc[j];
  }
}

// --------------------------------------------------------------------------
extern "C" void kernel_launch(void* const* d_in, const int* in_sizes, int n_in,
                              void* d_out, int out_size, void* d_ws,
                              size_t ws_size, hipStream_t stream) {
  const float* query = (const float*)d_in[0];  // [8,64,64,256]
  const float* hist = (const float*)d_in[1];   // [8,16,64,64,256]
  const float* Wq = (const float*)d_in[2];     // [256,128]
  const float* Wk = (const float*)d_in[3];     // [256,128]
  const float* Wv = (const float*)d_in[4];     // [256,128]
  const float* Wo = (const float*)d_in[5];     // [128,256]
  float* out = (float*)d_out;                  // [32768,256]

  float* ws = (float*)d_ws;
  float* M1 = ws;          // 65536 floats
  float* M2 = ws + 65536;  // 65536 floats

  precompute_weights<<<512, 256, 0, stream>>>(Wq, Wk, Wv, Wo, M1, M2);
  fused_all<<<512, 256, 0, stream>>>(query, hist, M1, M2, out);
}